// Round 17
// baseline (724.308 us; speedup 1.0000x reference)
//
#include <hip/hip_runtime.h>
#include <math.h>

typedef __attribute__((ext_vector_type(8))) short short8;
typedef __attribute__((ext_vector_type(4))) short short4v;
typedef __attribute__((ext_vector_type(4))) float f32x4;

__device__ __forceinline__ unsigned short f2b(float f) {
  unsigned u = __float_as_uint(f);
  return (unsigned short)((u + 0x7fffu + ((u >> 16) & 1u)) >> 16);
}
__device__ __forceinline__ float b2f(unsigned short h) {
  return __uint_as_float(((unsigned)h) << 16);
}
__device__ __forceinline__ f32x4 mfma16(short8 a, short8 b, f32x4 c) {
  return __builtin_amdgcn_mfma_f32_16x16x32_bf16(a, b, c, 0, 0, 0);
}
template <int STRIDE>
__device__ __forceinline__ short8 lds8(const short* buf, int row, int k) {
  int idx = (row * STRIDE + k) ^ ((row & 7) << 3);
  return *(const short8*)(buf + idx);
}
template <int STRIDE>
__device__ __forceinline__ void ldsw(short* buf, int row, int col, unsigned short v) {
  buf[(row * STRIDE + col) ^ ((row & 7) << 3)] = (short)v;
}
__device__ __forceinline__ float red16sum(float v) {
  v += __shfl_xor(v, 1); v += __shfl_xor(v, 2);
  v += __shfl_xor(v, 4); v += __shfl_xor(v, 8);
  return v;
}
__device__ __forceinline__ float red16max(float v) {
  v = fmaxf(v, __shfl_xor(v, 1)); v = fmaxf(v, __shfl_xor(v, 2));
  v = fmaxf(v, __shfl_xor(v, 4)); v = fmaxf(v, __shfl_xor(v, 8));
  return v;
}

// ---- async stage of one 16KB B-chunk: wave w copies bytes [w*4096, +4096) ----
__device__ __forceinline__ void stage16k(const short* __restrict__ g, short* l,
                                         int w, int lane) {
  const char* gb = (const char*)g + w * 4096 + lane * 16;
  char* lb = (char*)l + w * 4096;
#pragma unroll
  for (int c = 0; c < 4; ++c)
    __builtin_amdgcn_global_load_lds(
        (const __attribute__((address_space(1))) unsigned int*)(gb + c * 1024),
        (__attribute__((address_space(3))) unsigned int*)(lb + c * 1024), 16, 0, 0);
}

// ---- staged GEMM core: wave = 16 rows x 256 cols; 3-buffer, 1 barrier/step ----
template <int KB>
__device__ __forceinline__ void gemm_core(const short* __restrict__ A, int lda,
                                          const short* __restrict__ Wimg,
                                          short* sB, f32x4 acc[16], int r0,
                                          int w, int lane, int l15, int g4) {
  short8 af[KB];
#pragma unroll
  for (int kk = 0; kk < KB; ++kk)
    af[kk] = *(const short8*)(A + (size_t)(r0 + l15) * lda + kk * 32 + g4 * 8);
  stage16k(Wimg, sB, w, lane);
  stage16k(Wimg + 8192, sB + 8192, w, lane);
#pragma unroll
  for (int kb = 0; kb < KB; ++kb) {
    if (kb + 1 < KB) {
      asm volatile("s_waitcnt vmcnt(4)" ::: "memory");
    } else {
      asm volatile("s_waitcnt vmcnt(0)" ::: "memory");
    }
    __builtin_amdgcn_s_barrier();
    __builtin_amdgcn_sched_barrier(0);  // nothing moves above the barrier
    if (kb + 2 < KB)
      stage16k(Wimg + (kb + 2) * 8192, sB + ((kb + 2) % 3) * 8192, w, lane);
    const short* cur = sB + (kb % 3) * 8192;
#pragma unroll
    for (int tc = 0; tc < 16; ++tc) {
      int row = tc * 16 + l15;
      short8 bf = *(const short8*)(cur + ((row * 32 + g4 * 8) ^ ((row & 7) << 3)));
      acc[tc] = mfma16(af[kb], bf, acc[tc]);
    }
    __builtin_amdgcn_sched_barrier(0);  // reads stay within their step
  }
}

// ---- LN epilogue v2: residual in via coalesced LDS, LN, coalesced out ----
// Block tile = rows [r0b, r0b+64) x 256 cols = contiguous 32KB of x.
// sB (48KB stage buffer) is dead after gemm_core's final barrier.
__device__ __forceinline__ void ln_epi2(f32x4 acc[16], short* __restrict__ x,
                                        short* sB,
                                        const float* __restrict__ bias,
                                        const float* __restrict__ g_,
                                        const float* __restrict__ b_,
                                        int r0b, int w, int tid, int l15, int g4) {
  __syncthreads();  // all waves done with stage buffer
  const short* xsrc = x + (size_t)r0b * 256;
#pragma unroll
  for (int i = 0; i < 8; ++i) {
    int j = i * 256 + tid;
    int row = j >> 5, c8 = j & 31;
    short8 v = *(const short8*)(xsrc + j * 8);
    *(short8*)(sB + ((row * 256 + c8 * 8) ^ ((row & 7) << 3))) = v;
  }
  __syncthreads();
  float s1[4] = {0.f, 0.f, 0.f, 0.f}, s2[4] = {0.f, 0.f, 0.f, 0.f};
#pragma unroll
  for (int tc = 0; tc < 16; ++tc) {
    int col = tc * 16 + l15;
    float bv = bias[col];
#pragma unroll
    for (int r = 0; r < 4; ++r) {
      int lrow = w * 16 + g4 * 4 + r;
      float v = acc[tc][r] + bv +
                b2f((unsigned short)sB[(lrow * 256 + col) ^ ((lrow & 7) << 3)]);
      acc[tc][r] = v;
      s1[r] += v; s2[r] += v * v;
    }
  }
  float mean[4], rstd[4];
#pragma unroll
  for (int r = 0; r < 4; ++r) {
    float a = red16sum(s1[r]), qq = red16sum(s2[r]);
    mean[r] = a * (1.f / 256.f);
    rstd[r] = rsqrtf(qq * (1.f / 256.f) - mean[r] * mean[r] + 1e-12f);
  }
  __syncthreads();  // residual reads done before overwrite
#pragma unroll
  for (int tc = 0; tc < 16; ++tc) {
    int col = tc * 16 + l15;
    float gv = g_[col], bv = b_[col];
#pragma unroll
    for (int r = 0; r < 4; ++r) {
      int lrow = w * 16 + g4 * 4 + r;
      sB[(lrow * 256 + col) ^ ((lrow & 7) << 3)] =
          (short)f2b((acc[tc][r] - mean[r]) * rstd[r] * gv + bv);
    }
  }
  __syncthreads();
  short* xdst = x + (size_t)r0b * 256;
#pragma unroll
  for (int i = 0; i < 8; ++i) {
    int j = i * 256 + tid;
    int row = j >> 5, c8 = j & 31;
    short8 v = *(const short8*)(sB + ((row * 256 + c8 * 8) ^ ((row & 7) << 3)));
    *(short8*)(xdst + j * 8) = v;
  }
}

// ---- weight prep: f32 [K][N] -> pre-swizzled bf16 LDS-image chunks ----
// shorts: WQ 0 | WK 131072 | WV 262144 | WO 393216 | WI 524288 | WOUT 786432 | WP 1048576
__global__ void prep_w(const float* __restrict__ qw, const float* __restrict__ kw,
                       const float* __restrict__ vw, const float* __restrict__ ow,
                       const float* __restrict__ iw, const float* __restrict__ outw,
                       const float* __restrict__ pw, short* __restrict__ ws) {
  int t = blockIdx.x * 256 + threadIdx.x;  // 1,114,112 total
  float val; int base, n, k;
  if (t < 524288) {
    int which = t >> 17, r = t & 131071;
    int ly = r >> 16, e = r & 65535;
    n = e >> 8; k = e & 255;
    const float* m = which == 0 ? qw : which == 1 ? kw : which == 2 ? vw : ow;
    val = m[(ly * 256 + k) * 256 + n];
    base = which * 131072 + ly * 65536;
  } else if (t < 786432) {
    int e = t - 524288;
    int ly = e >> 17, f = e & 131071, g2 = f >> 16, e2 = f & 65535;
    n = e2 >> 8; k = e2 & 255;
    val = iw[(ly * 256 + k) * 512 + g2 * 256 + n];
    base = 524288 + ly * 131072 + g2 * 65536;
  } else if (t < 1048576) {
    int e = t - 786432;
    int ly = e >> 17, f = e & 131071;
    n = f >> 9; k = f & 511;
    val = outw[(ly * 512 + k) * 256 + n];
    base = 786432 + ly * 131072;
  } else {
    int e = t - 1048576;
    n = e >> 8; k = e & 255;
    val = pw[k * 256 + n];
    base = 1048576;
  }
  int pos = ((n * 32 + (k & 31)) ^ ((n & 7) << 3));
  ws[base + (k >> 5) * 8192 + pos] = (short)f2b(val);
}

// ---- embedding + LN: wave = one token ----
__global__ __launch_bounds__(256) void emb_k(
    const int* __restrict__ word, const int* __restrict__ age,
    const int* __restrict__ seg, const int* __restrict__ posi,
    const float* __restrict__ we, const float* __restrict__ se,
    const float* __restrict__ ae, const float* __restrict__ pe,
    const float* __restrict__ g, const float* __restrict__ b,
    short* __restrict__ x) {
  int w = threadIdx.x >> 6, lane = threadIdx.x & 63;
  int t = blockIdx.x * 4 + w;
  int wi = word[t], gi = seg[t], ai = age[t], pi = posi[t];
  f32x4 e = ((const f32x4*)(we + wi * 256))[lane];
  f32x4 tv = ((const f32x4*)(se + gi * 256))[lane]; e = e + tv;
  tv = ((const f32x4*)(ae + ai * 256))[lane]; e = e + tv;
  tv = ((const f32x4*)(pe + pi * 256))[lane]; e = e + tv;
  float s1 = e[0] + e[1] + e[2] + e[3];
  float s2 = e[0] * e[0] + e[1] * e[1] + e[2] * e[2] + e[3] * e[3];
#pragma unroll
  for (int m = 1; m < 64; m <<= 1) { s1 += __shfl_xor(s1, m); s2 += __shfl_xor(s2, m); }
  float mean = s1 * (1.f / 256.f);
  float rstd = rsqrtf(s2 * (1.f / 256.f) - mean * mean + 1e-12f);
  f32x4 gv = ((const f32x4*)g)[lane];
  f32x4 bv = ((const f32x4*)b)[lane];
  short4v pk;
#pragma unroll
  for (int j = 0; j < 4; ++j) pk[j] = (short)f2b((e[j] - mean) * rstd * gv[j] + bv[j]);
  *(short4v*)(x + t * 256 + lane * 4) = pk;
}

// ---- QKV: grid (1600, 3); LDS-repacked epilogue, coalesced short8 copy-out ----
__global__ __launch_bounds__(256) void qkv3_k(
    const short* __restrict__ x, const short* __restrict__ img,
    const float* __restrict__ qb_, const float* __restrict__ kb_,
    const float* __restrict__ vb_,
    short* __restrict__ q, short* __restrict__ k2, short* __restrict__ vt, int ly) {
  __shared__ __align__(16) short sB[24576];
  int tid = threadIdx.x;
  int w = tid >> 6, lane = tid & 63;
  int l15 = lane & 15, g4 = lane >> 4;
  int y = blockIdx.y;
  int r0b = blockIdx.x * 64;
  int r0 = r0b + w * 16;
  const short* W = img + y * 131072 + ly * 65536;
  const float* bias = (y == 0 ? qb_ : y == 1 ? kb_ : vb_) + ly * 256;
  f32x4 acc[16];
#pragma unroll
  for (int i = 0; i < 16; ++i) acc[i] = f32x4{0.f, 0.f, 0.f, 0.f};
  gemm_core<8>(x, 256, W, sB, acc, r0, w, lane, l15, g4);
  __syncthreads();  // stage buffer dead for ALL waves -> reuse as repack area
  if (y < 2) {
#pragma unroll
    for (int tc = 0; tc < 16; ++tc) {
      int col = tc * 16 + l15;
      float bv = bias[col];
#pragma unroll
      for (int r = 0; r < 4; ++r) {
        int lrow = w * 16 + g4 * 4 + r;
        sB[(lrow * 256 + col) ^ ((lrow & 7) << 3)] = (short)f2b(acc[tc][r] + bv);
      }
    }
    __syncthreads();
    short* out = (y ? k2 : q) + (size_t)r0b * 256;
#pragma unroll
    for (int i = 0; i < 8; ++i) {
      int j = i * 256 + tid;
      int row = j >> 5, c8 = j & 31;
      short8 v = *(const short8*)(sB + ((row * 256 + c8 * 8) ^ ((row & 7) << 3)));
      *(short8*)(out + j * 8) = v;
    }
  } else {
    // vt layout per seq: [d=256][tok=64]; block = exactly one seq
#pragma unroll
    for (int tc = 0; tc < 16; ++tc) {
      int d = tc * 16 + l15;
      float bv = bias[d];
#pragma unroll
      for (int r = 0; r < 4; ++r) {
        int tok = w * 16 + g4 * 4 + r;
        sB[(d * 64 + tok) ^ ((d & 7) << 3)] = (short)f2b(acc[tc][r] + bv);
      }
    }
    __syncthreads();
    short* dst = vt + (size_t)blockIdx.x * 16384;
#pragma unroll
    for (int i = 0; i < 8; ++i) {
      int j = i * 256 + tid;
      int d = j >> 3, t8 = j & 7;
      short8 v = *(const short8*)(sB + ((d * 64 + t8 * 8) ^ ((d & 7) << 3)));
      *(short8*)(dst + d * 64 + t8 * 8) = v;
    }
  }
}

// ---- attention: block = seq, wave = head; wave-local softmax; ctx -> global ----
__global__ __launch_bounds__(256) void attn_k(
    const short* __restrict__ q, const short* __restrict__ k,
    const short* __restrict__ vt, short* __restrict__ ctx,
    const float* __restrict__ mask) {
  __shared__ __align__(16) short sP[16384];  // 4 waves x [64][64]
  int w = threadIdx.x >> 6, lane = threadIdx.x & 63;
  int l15 = lane & 15, g4 = lane >> 4;
  int n = blockIdx.x;
  const f32x4 zero4 = {0.f, 0.f, 0.f, 0.f};
  short* sPw = sP + w * 4096;

  float amvr[4];
#pragma unroll
  for (int tc = 0; tc < 4; ++tc)
    amvr[tc] = (1.f - mask[n * 64 + tc * 16 + l15]) * -10000.f;

  const short* qn = q + (size_t)n * 16384;
  const short* kn = k + (size_t)n * 16384;
  const short* vtn = vt + (size_t)n * 16384;

  short8 qa[4][2];
#pragma unroll
  for (int st = 0; st < 4; ++st)
#pragma unroll
    for (int ks = 0; ks < 2; ++ks)
      qa[st][ks] = *(const short8*)(qn + (st * 16 + l15) * 256 + w * 64 + ks * 32 + g4 * 8);
  f32x4 sacc[4][4];
#pragma unroll
  for (int st = 0; st < 4; ++st)
#pragma unroll
    for (int tc = 0; tc < 4; ++tc) sacc[st][tc] = zero4;
#pragma unroll
  for (int ks = 0; ks < 2; ++ks)
#pragma unroll
    for (int tc = 0; tc < 4; ++tc) {
      short8 kf = *(const short8*)(kn + (tc * 16 + l15) * 256 + w * 64 + ks * 32 + g4 * 8);
#pragma unroll
      for (int st = 0; st < 4; ++st) sacc[st][tc] = mfma16(qa[st][ks], kf, sacc[st][tc]);
    }
#pragma unroll
  for (int st = 0; st < 4; ++st)
#pragma unroll
    for (int r = 0; r < 4; ++r) {
      float pv[4];
      float mx = -1e30f;
#pragma unroll
      for (int tc = 0; tc < 4; ++tc) {
        float sv = sacc[st][tc][r] * 0.125f + amvr[tc];
        pv[tc] = sv;
        mx = fmaxf(mx, sv);
      }
      mx = red16max(mx);
      float sm = 0.f;
#pragma unroll
      for (int tc = 0; tc < 4; ++tc) {
        float e = __expf(pv[tc] - mx);
        pv[tc] = e;
        sm += e;
      }
      sm = red16sum(sm);
      float inv = 1.f / sm;
#pragma unroll
      for (int tc = 0; tc < 4; ++tc)
        ldsw<64>(sPw, st * 16 + g4 * 4 + r, tc * 16 + l15, f2b(pv[tc] * inv));
    }
  __syncthreads();  // also orders q-reads (above) vs ctx-writes (below)

  f32x4 cacc[4][4];
#pragma unroll
  for (int st = 0; st < 4; ++st)
#pragma unroll
    for (int tc = 0; tc < 4; ++tc) cacc[st][tc] = zero4;
#pragma unroll
  for (int ks = 0; ks < 2; ++ks) {
    short8 pa[4];
#pragma unroll
    for (int st = 0; st < 4; ++st) pa[st] = lds8<64>(sPw, st * 16 + l15, ks * 32 + g4 * 8);
#pragma unroll
    for (int tc = 0; tc < 4; ++tc) {
      short8 vf = *(const short8*)(vtn + (w * 64 + tc * 16 + l15) * 64 + ks * 32 + g4 * 8);
#pragma unroll
      for (int st = 0; st < 4; ++st) cacc[st][tc] = mfma16(pa[st], vf, cacc[st][tc]);
    }
  }
#pragma unroll
  for (int st = 0; st < 4; ++st)
#pragma unroll
    for (int tc = 0; tc < 4; ++tc)
#pragma unroll
      for (int r = 0; r < 4; ++r)
        ctx[((size_t)n * 64 + st * 16 + g4 * 4 + r) * 256 + w * 64 + tc * 16 + l15] =
            (short)f2b(cacc[st][tc][r]);
}

// ---- O-proj + residual LN: x = LN(ctx@wo + ob + x); coalesced epilogue ----
__global__ __launch_bounds__(256) void oln_k(
    const short* __restrict__ ctx, const short* __restrict__ img,
    const float* __restrict__ bias, short* __restrict__ x,
    const float* __restrict__ g_, const float* __restrict__ b_) {
  __shared__ __align__(16) short sB[24576];
  int tid = threadIdx.x;
  int w = tid >> 6, lane = tid & 63;
  int l15 = lane & 15, g4 = lane >> 4;
  int r0b = blockIdx.x * 64;
  f32x4 acc[16];
#pragma unroll
  for (int i = 0; i < 16; ++i) acc[i] = f32x4{0.f, 0.f, 0.f, 0.f};
  gemm_core<8>(ctx, 256, img, sB, acc, r0b + w * 16, w, lane, l15, g4);
  ln_epi2(acc, x, sB, bias, g_, b_, r0b, w, tid, l15, g4);
}

// ---- FFN1: grid (1600, 2); gelu via exp; repacked coalesced h-store ----
__global__ __launch_bounds__(256) void ffn1_k(
    const short* __restrict__ x, const short* __restrict__ img,
    const float* __restrict__ bias, short* __restrict__ h) {
  __shared__ __align__(16) short sB[24576];
  int tid = threadIdx.x;
  int w = tid >> 6, lane = tid & 63;
  int l15 = lane & 15, g4 = lane >> 4;
  int y = blockIdx.y;
  int r0b = blockIdx.x * 64;
  f32x4 acc[16];
#pragma unroll
  for (int i = 0; i < 16; ++i) acc[i] = f32x4{0.f, 0.f, 0.f, 0.f};
  gemm_core<8>(x, 256, img + y * 65536, sB, acc, r0b + w * 16, w, lane, l15, g4);
  __syncthreads();  // stage buffer dead -> repack area
  const float* bs = bias + y * 256;
#pragma unroll
  for (int tc = 0; tc < 16; ++tc) {
    int col = tc * 16 + l15;
    float bv = bs[col];
#pragma unroll
    for (int r = 0; r < 4; ++r) {
      float v = acc[tc][r] + bv;
      // tanh-form GELU via exp: v * sigmoid(1.5957691*(v + 0.044715 v^3))
      float z = 1.5957691f * (v + 0.044715f * v * v * v);
      v = v / (1.f + __expf(-z));
      int lrow = w * 16 + g4 * 4 + r;
      sB[(lrow * 256 + col) ^ ((lrow & 7) << 3)] = (short)f2b(v);
    }
  }
  __syncthreads();
  short* dst = h + (size_t)r0b * 512 + y * 256;
#pragma unroll
  for (int i = 0; i < 8; ++i) {
    int j = i * 256 + tid;
    int row = j >> 5, c8 = j & 31;
    short8 v = *(const short8*)(sB + ((row * 256 + c8 * 8) ^ ((row & 7) << 3)));
    *(short8*)(dst + row * 512 + c8 * 8) = v;
  }
}

// ---- FFN2 + residual LN: x = LN(h@wout + outb + x); coalesced epilogue ----
__global__ __launch_bounds__(256) void ffn2_k(
    const short* __restrict__ h, const short* __restrict__ img,
    const float* __restrict__ bias, short* __restrict__ x,
    const float* __restrict__ g_, const float* __restrict__ b_) {
  __shared__ __align__(16) short sB[24576];
  int tid = threadIdx.x;
  int w = tid >> 6, lane = tid & 63;
  int l15 = lane & 15, g4 = lane >> 4;
  int r0b = blockIdx.x * 64;
  f32x4 acc[16];
#pragma unroll
  for (int i = 0; i < 16; ++i) acc[i] = f32x4{0.f, 0.f, 0.f, 0.f};
  gemm_core<16>(h, 512, img, sB, acc, r0b + w * 16, w, lane, l15, g4);
  ln_epi2(acc, x, sB, bias, g_, b_, r0b, w, tid, l15, g4);
}

// ---- pooler: 25 blocks; rows = seqs, A = first token of each seq ----
__global__ __launch_bounds__(256) void pool_k(
    const short* __restrict__ x, const short* __restrict__ img,
    const float* __restrict__ pb, float* __restrict__ out) {
  __shared__ __align__(16) short sB[24576];
  int w = threadIdx.x >> 6, lane = threadIdx.x & 63;
  int l15 = lane & 15, g4 = lane >> 4;
  int r0 = blockIdx.x * 64 + w * 16;  // seq index (25*64 = 1600 exact)
  f32x4 acc[16];
#pragma unroll
  for (int i = 0; i < 16; ++i) acc[i] = f32x4{0.f, 0.f, 0.f, 0.f};
  gemm_core<8>(x, 16384, img, sB, acc, r0, w, lane, l15, g4);
#pragma unroll
  for (int tc = 0; tc < 16; ++tc) {
    int col = tc * 16 + l15;
    float bv = pb[col];
#pragma unroll
    for (int r = 0; r < 4; ++r)
      out[(size_t)(r0 + g4 * 4 + r) * 256 + col] = tanhf(acc[tc][r] + bv);
  }
}

extern "C" void kernel_launch(void* const* d_in, const int* in_sizes, int n_in,
                              void* d_out, int out_size, void* d_ws, size_t ws_size,
                              hipStream_t stream) {
  const int* word = (const int*)d_in[0];
  const int* age = (const int*)d_in[1];
  const int* seg = (const int*)d_in[2];
  const int* posi = (const int*)d_in[3];
  const float* mask = (const float*)d_in[4];
  const float* word_emb = (const float*)d_in[6];
  const float* seg_emb = (const float*)d_in[7];
  const float* age_emb = (const float*)d_in[8];
  const float* posi_emb = (const float*)d_in[9];
  const float* emb_g = (const float*)d_in[10];
  const float* emb_b = (const float*)d_in[11];
  const float* qw = (const float*)d_in[12];
  const float* qb = (const float*)d_in[13];
  const float* kw = (const float*)d_in[14];
  const float* kb = (const float*)d_in[15];
  const float* vw = (const float*)d_in[16];
  const float* vb = (const float*)d_in[17];
  const float* ow = (const float*)d_in[18];
  const float* ob = (const float*)d_in[19];
  const float* attn_g = (const float*)d_in[20];
  const float* attn_b = (const float*)d_in[21];
  const float* iw = (const float*)d_in[22];
  const float* ib = (const float*)d_in[23];
  const float* outw = (const float*)d_in[24];
  const float* outb = (const float*)d_in[25];
  const float* out_g = (const float*)d_in[26];
  const float* out_b = (const float*)d_in[27];
  const float* pool_w = (const float*)d_in[28];
  const float* pool_b = (const float*)d_in[29];
  short* ws = (short*)d_ws;

  // layout (shorts): img 1,114,112 | x 26,214,400 | q | k | vt  (h = q..k span)
  short* xb_ = ws + 1114112;
  short* qbuf = xb_ + 26214400;
  short* kbuf = qbuf + 26214400;
  short* vtbuf = kbuf + 26214400;
  short* hbuf = qbuf;  // 102400x512, overlaps q+k (dead by FFN time)

  prep_w<<<4352, 256, 0, stream>>>(qw, kw, vw, ow, iw, outw, pool_w, ws);
  emb_k<<<25600, 256, 0, stream>>>(word, age, seg, posi, word_emb, seg_emb,
                                   age_emb, posi_emb, emb_g, emb_b, xb_);
  for (int ly = 0; ly < 2; ++ly) {
    qkv3_k<<<dim3(1600, 3), 256, 0, stream>>>(xb_, ws, qb, kb, vb, qbuf, kbuf,
                                              vtbuf, ly);
    attn_k<<<1600, 256, 0, stream>>>(qbuf, kbuf, vtbuf, qbuf, mask);
    oln_k<<<1600, 256, 0, stream>>>(qbuf, ws + 393216 + ly * 65536, ob + ly * 256,
                                    xb_, attn_g + ly * 256, attn_b + ly * 256);
    ffn1_k<<<dim3(1600, 2), 256, 0, stream>>>(xb_, ws + 524288 + ly * 131072,
                                              ib + ly * 512, hbuf);
    ffn2_k<<<1600, 256, 0, stream>>>(hbuf, ws + 786432 + ly * 131072,
                                     outb + ly * 256, xb_, out_g + ly * 256,
                                     out_b + ly * 256);
  }
  pool_k<<<25, 256, 0, stream>>>(xb_, ws + 1048576, pool_b, (float*)d_out);
}

// Round 18
// 630.858 us; speedup vs baseline: 1.1481x; 1.1481x over previous
//
#include <hip/hip_runtime.h>
#include <math.h>

typedef __attribute__((ext_vector_type(8))) short short8;
typedef __attribute__((ext_vector_type(4))) short short4v;
typedef __attribute__((ext_vector_type(4))) float f32x4;

__device__ __forceinline__ unsigned short f2b(float f) {
  unsigned u = __float_as_uint(f);
  return (unsigned short)((u + 0x7fffu + ((u >> 16) & 1u)) >> 16);
}
__device__ __forceinline__ float b2f(unsigned short h) {
  return __uint_as_float(((unsigned)h) << 16);
}
__device__ __forceinline__ f32x4 mfma16(short8 a, short8 b, f32x4 c) {
  return __builtin_amdgcn_mfma_f32_16x16x32_bf16(a, b, c, 0, 0, 0);
}
template <int STRIDE>
__device__ __forceinline__ short8 lds8(const short* buf, int row, int k) {
  int idx = (row * STRIDE + k) ^ ((row & 7) << 3);
  return *(const short8*)(buf + idx);
}
template <int STRIDE>
__device__ __forceinline__ void ldsw(short* buf, int row, int col, unsigned short v) {
  buf[(row * STRIDE + col) ^ ((row & 7) << 3)] = (short)v;
}
__device__ __forceinline__ float red16sum(float v) {
  v += __shfl_xor(v, 1); v += __shfl_xor(v, 2);
  v += __shfl_xor(v, 4); v += __shfl_xor(v, 8);
  return v;
}
__device__ __forceinline__ float red16max(float v) {
  v = fmaxf(v, __shfl_xor(v, 1)); v = fmaxf(v, __shfl_xor(v, 2));
  v = fmaxf(v, __shfl_xor(v, 4)); v = fmaxf(v, __shfl_xor(v, 8));
  return v;
}

// ---- async stage of one 16KB B-chunk: wave w copies bytes [w*4096, +4096) ----
__device__ __forceinline__ void stage16k(const short* __restrict__ g, short* l,
                                         int w, int lane) {
  const char* gb = (const char*)g + w * 4096 + lane * 16;
  char* lb = (char*)l + w * 4096;
#pragma unroll
  for (int c = 0; c < 4; ++c)
    __builtin_amdgcn_global_load_lds(
        (const __attribute__((address_space(1))) unsigned int*)(gb + c * 1024),
        (__attribute__((address_space(3))) unsigned int*)(lb + c * 1024), 16, 0, 0);
}

// ---- staged GEMM core: wave = 16 rows x 256 cols; 3-buffer, 1 barrier/step ----
template <int KB>
__device__ __forceinline__ void gemm_core(const short* __restrict__ A, int lda,
                                          const short* __restrict__ Wimg,
                                          short* sB, f32x4 acc[16], int r0,
                                          int w, int lane, int l15, int g4) {
  short8 af[KB];
#pragma unroll
  for (int kk = 0; kk < KB; ++kk)
    af[kk] = *(const short8*)(A + (size_t)(r0 + l15) * lda + kk * 32 + g4 * 8);
  stage16k(Wimg, sB, w, lane);
  stage16k(Wimg + 8192, sB + 8192, w, lane);
#pragma unroll
  for (int kb = 0; kb < KB; ++kb) {
    if (kb + 1 < KB) {
      asm volatile("s_waitcnt vmcnt(4)" ::: "memory");
    } else {
      asm volatile("s_waitcnt vmcnt(0)" ::: "memory");
    }
    __builtin_amdgcn_s_barrier();
    __builtin_amdgcn_sched_barrier(0);  // nothing moves above the barrier
    if (kb + 2 < KB)
      stage16k(Wimg + (kb + 2) * 8192, sB + ((kb + 2) % 3) * 8192, w, lane);
    const short* cur = sB + (kb % 3) * 8192;
#pragma unroll
    for (int tc = 0; tc < 16; ++tc) {
      int row = tc * 16 + l15;
      short8 bf = *(const short8*)(cur + ((row * 32 + g4 * 8) ^ ((row & 7) << 3)));
      acc[tc] = mfma16(af[kb], bf, acc[tc]);
    }
    __builtin_amdgcn_sched_barrier(0);  // reads stay within their step
  }
}

// ---- LN epilogue: x = LN(acc + bias + x), wave-row-owned ----
__device__ __forceinline__ void ln_epi(f32x4 acc[16], short* x,
                                       const float* __restrict__ bias,
                                       const float* __restrict__ g_,
                                       const float* __restrict__ b_,
                                       int r0, int l15, int g4) {
  float s1[4] = {0.f, 0.f, 0.f, 0.f}, s2[4] = {0.f, 0.f, 0.f, 0.f};
#pragma unroll
  for (int tc = 0; tc < 16; ++tc) {
    int col = tc * 16 + l15;
    float bv = bias[col];
#pragma unroll
    for (int r = 0; r < 4; ++r) {
      float v = acc[tc][r] + bv + b2f((unsigned short)x[(r0 + g4 * 4 + r) * 256 + col]);
      acc[tc][r] = v;
      s1[r] += v; s2[r] += v * v;
    }
  }
  float mean[4], rstd[4];
#pragma unroll
  for (int r = 0; r < 4; ++r) {
    float a = red16sum(s1[r]), q = red16sum(s2[r]);
    mean[r] = a * (1.f / 256.f);
    rstd[r] = rsqrtf(q * (1.f / 256.f) - mean[r] * mean[r] + 1e-12f);
  }
#pragma unroll
  for (int tc = 0; tc < 16; ++tc) {
    int col = tc * 16 + l15;
    float gv = g_[col], bv = b_[col];
#pragma unroll
    for (int r = 0; r < 4; ++r)
      x[(r0 + g4 * 4 + r) * 256 + col] =
          (short)f2b((acc[tc][r] - mean[r]) * rstd[r] * gv + bv);
  }
}

// ---- weight prep: f32 [K][N] -> pre-swizzled bf16 LDS-image chunks ----
// shorts: WQ 0 | WK 131072 | WV 262144 | WO 393216 | WI 524288 | WOUT 786432 | WP 1048576
__global__ void prep_w(const float* __restrict__ qw, const float* __restrict__ kw,
                       const float* __restrict__ vw, const float* __restrict__ ow,
                       const float* __restrict__ iw, const float* __restrict__ outw,
                       const float* __restrict__ pw, short* __restrict__ ws) {
  int t = blockIdx.x * 256 + threadIdx.x;  // 1,114,112 total
  float val; int base, n, k;
  if (t < 524288) {
    int which = t >> 17, r = t & 131071;
    int ly = r >> 16, e = r & 65535;
    n = e >> 8; k = e & 255;
    const float* m = which == 0 ? qw : which == 1 ? kw : which == 2 ? vw : ow;
    val = m[(ly * 256 + k) * 256 + n];
    base = which * 131072 + ly * 65536;
  } else if (t < 786432) {
    int e = t - 524288;
    int ly = e >> 17, f = e & 131071, g2 = f >> 16, e2 = f & 65535;
    n = e2 >> 8; k = e2 & 255;
    val = iw[(ly * 256 + k) * 512 + g2 * 256 + n];
    base = 524288 + ly * 131072 + g2 * 65536;
  } else if (t < 1048576) {
    int e = t - 786432;
    int ly = e >> 17, f = e & 131071;
    n = f >> 9; k = f & 511;
    val = outw[(ly * 512 + k) * 256 + n];
    base = 786432 + ly * 131072;
  } else {
    int e = t - 1048576;
    n = e >> 8; k = e & 255;
    val = pw[k * 256 + n];
    base = 1048576;
  }
  int pos = ((n * 32 + (k & 31)) ^ ((n & 7) << 3));
  ws[base + (k >> 5) * 8192 + pos] = (short)f2b(val);
}

// ---- embedding + LN: wave = one token ----
__global__ __launch_bounds__(256) void emb_k(
    const int* __restrict__ word, const int* __restrict__ age,
    const int* __restrict__ seg, const int* __restrict__ posi,
    const float* __restrict__ we, const float* __restrict__ se,
    const float* __restrict__ ae, const float* __restrict__ pe,
    const float* __restrict__ g, const float* __restrict__ b,
    short* __restrict__ x) {
  int w = threadIdx.x >> 6, lane = threadIdx.x & 63;
  int t = blockIdx.x * 4 + w;
  int wi = word[t], gi = seg[t], ai = age[t], pi = posi[t];
  f32x4 e = ((const f32x4*)(we + wi * 256))[lane];
  f32x4 tv = ((const f32x4*)(se + gi * 256))[lane]; e = e + tv;
  tv = ((const f32x4*)(ae + ai * 256))[lane]; e = e + tv;
  tv = ((const f32x4*)(pe + pi * 256))[lane]; e = e + tv;
  float s1 = e[0] + e[1] + e[2] + e[3];
  float s2 = e[0] * e[0] + e[1] * e[1] + e[2] * e[2] + e[3] * e[3];
#pragma unroll
  for (int m = 1; m < 64; m <<= 1) { s1 += __shfl_xor(s1, m); s2 += __shfl_xor(s2, m); }
  float mean = s1 * (1.f / 256.f);
  float rstd = rsqrtf(s2 * (1.f / 256.f) - mean * mean + 1e-12f);
  f32x4 gv = ((const f32x4*)g)[lane];
  f32x4 bv = ((const f32x4*)b)[lane];
  short4v pk;
#pragma unroll
  for (int j = 0; j < 4; ++j) pk[j] = (short)f2b((e[j] - mean) * rstd * gv[j] + bv[j]);
  *(short4v*)(x + t * 256 + lane * 4) = pk;
}

// ---- QKV: grid (1600, 3); LDS-repacked epilogue, coalesced short8 copy-out ----
__global__ __launch_bounds__(256) void qkv3_k(
    const short* __restrict__ x, const short* __restrict__ img,
    const float* __restrict__ qb_, const float* __restrict__ kb_,
    const float* __restrict__ vb_,
    short* __restrict__ q, short* __restrict__ k2, short* __restrict__ vt, int ly) {
  __shared__ __align__(16) short sB[24576];
  int tid = threadIdx.x;
  int w = tid >> 6, lane = tid & 63;
  int l15 = lane & 15, g4 = lane >> 4;
  int y = blockIdx.y;
  int r0b = blockIdx.x * 64;
  int r0 = r0b + w * 16;
  const short* W = img + y * 131072 + ly * 65536;
  const float* bias = (y == 0 ? qb_ : y == 1 ? kb_ : vb_) + ly * 256;
  f32x4 acc[16];
#pragma unroll
  for (int i = 0; i < 16; ++i) acc[i] = f32x4{0.f, 0.f, 0.f, 0.f};
  gemm_core<8>(x, 256, W, sB, acc, r0, w, lane, l15, g4);
  __syncthreads();  // stage buffer dead for ALL waves -> reuse as repack area
  if (y < 2) {
#pragma unroll
    for (int tc = 0; tc < 16; ++tc) {
      int col = tc * 16 + l15;
      float bv = bias[col];
#pragma unroll
      for (int r = 0; r < 4; ++r) {
        int lrow = w * 16 + g4 * 4 + r;
        sB[(lrow * 256 + col) ^ ((lrow & 7) << 3)] = (short)f2b(acc[tc][r] + bv);
      }
    }
    __syncthreads();
    short* out = (y ? k2 : q) + (size_t)r0b * 256;
#pragma unroll
    for (int i = 0; i < 8; ++i) {
      int j = i * 256 + tid;
      int row = j >> 5, c8 = j & 31;
      short8 v = *(const short8*)(sB + ((row * 256 + c8 * 8) ^ ((row & 7) << 3)));
      *(short8*)(out + j * 8) = v;
    }
  } else {
    // vt layout per seq: [d=256][tok=64]; block = exactly one seq
#pragma unroll
    for (int tc = 0; tc < 16; ++tc) {
      int d = tc * 16 + l15;
      float bv = bias[d];
#pragma unroll
      for (int r = 0; r < 4; ++r) {
        int tok = w * 16 + g4 * 4 + r;
        sB[(d * 64 + tok) ^ ((d & 7) << 3)] = (short)f2b(acc[tc][r] + bv);
      }
    }
    __syncthreads();
    short* dst = vt + (size_t)blockIdx.x * 16384;
#pragma unroll
    for (int i = 0; i < 8; ++i) {
      int j = i * 256 + tid;
      int d = j >> 3, t8 = j & 7;
      short8 v = *(const short8*)(sB + ((d * 64 + t8 * 8) ^ ((d & 7) << 3)));
      *(short8*)(dst + d * 64 + t8 * 8) = v;
    }
  }
}

// ---- attention: block = seq, wave = head; wave-local softmax; ctx -> global ----
__global__ __launch_bounds__(256) void attn_k(
    const short* __restrict__ q, const short* __restrict__ k,
    const short* __restrict__ vt, short* __restrict__ ctx,
    const float* __restrict__ mask) {
  __shared__ __align__(16) short sP[16384];  // 4 waves x [64][64]
  int w = threadIdx.x >> 6, lane = threadIdx.x & 63;
  int l15 = lane & 15, g4 = lane >> 4;
  int n = blockIdx.x;
  const f32x4 zero4 = {0.f, 0.f, 0.f, 0.f};
  short* sPw = sP + w * 4096;

  float amvr[4];
#pragma unroll
  for (int tc = 0; tc < 4; ++tc)
    amvr[tc] = (1.f - mask[n * 64 + tc * 16 + l15]) * -10000.f;

  const short* qn = q + (size_t)n * 16384;
  const short* kn = k + (size_t)n * 16384;
  const short* vtn = vt + (size_t)n * 16384;

  short8 qa[4][2];
#pragma unroll
  for (int st = 0; st < 4; ++st)
#pragma unroll
    for (int ks = 0; ks < 2; ++ks)
      qa[st][ks] = *(const short8*)(qn + (st * 16 + l15) * 256 + w * 64 + ks * 32 + g4 * 8);
  f32x4 sacc[4][4];
#pragma unroll
  for (int st = 0; st < 4; ++st)
#pragma unroll
    for (int tc = 0; tc < 4; ++tc) sacc[st][tc] = zero4;
#pragma unroll
  for (int ks = 0; ks < 2; ++ks)
#pragma unroll
    for (int tc = 0; tc < 4; ++tc) {
      short8 kf = *(const short8*)(kn + (tc * 16 + l15) * 256 + w * 64 + ks * 32 + g4 * 8);
#pragma unroll
      for (int st = 0; st < 4; ++st) sacc[st][tc] = mfma16(qa[st][ks], kf, sacc[st][tc]);
    }
#pragma unroll
  for (int st = 0; st < 4; ++st)
#pragma unroll
    for (int r = 0; r < 4; ++r) {
      float pv[4];
      float mx = -1e30f;
#pragma unroll
      for (int tc = 0; tc < 4; ++tc) {
        float sv = sacc[st][tc][r] * 0.125f + amvr[tc];
        pv[tc] = sv;
        mx = fmaxf(mx, sv);
      }
      mx = red16max(mx);
      float sm = 0.f;
#pragma unroll
      for (int tc = 0; tc < 4; ++tc) {
        float e = __expf(pv[tc] - mx);
        pv[tc] = e;
        sm += e;
      }
      sm = red16sum(sm);
      float inv = 1.f / sm;
#pragma unroll
      for (int tc = 0; tc < 4; ++tc)
        ldsw<64>(sPw, st * 16 + g4 * 4 + r, tc * 16 + l15, f2b(pv[tc] * inv));
    }
  __syncthreads();  // also orders q-reads (above) vs ctx-writes (below)

  f32x4 cacc[4][4];
#pragma unroll
  for (int st = 0; st < 4; ++st)
#pragma unroll
    for (int tc = 0; tc < 4; ++tc) cacc[st][tc] = zero4;
#pragma unroll
  for (int ks = 0; ks < 2; ++ks) {
    short8 pa[4];
#pragma unroll
    for (int st = 0; st < 4; ++st) pa[st] = lds8<64>(sPw, st * 16 + l15, ks * 32 + g4 * 8);
#pragma unroll
    for (int tc = 0; tc < 4; ++tc) {
      short8 vf = *(const short8*)(vtn + (w * 64 + tc * 16 + l15) * 64 + ks * 32 + g4 * 8);
#pragma unroll
      for (int st = 0; st < 4; ++st) cacc[st][tc] = mfma16(pa[st], vf, cacc[st][tc]);
    }
  }
#pragma unroll
  for (int st = 0; st < 4; ++st)
#pragma unroll
    for (int tc = 0; tc < 4; ++tc)
#pragma unroll
      for (int r = 0; r < 4; ++r)
        ctx[((size_t)n * 64 + st * 16 + g4 * 4 + r) * 256 + w * 64 + tc * 16 + l15] =
            (short)f2b(cacc[st][tc][r]);
}

// ---- O-proj + residual LN: x = LN(ctx@wo + ob + x) ----
__global__ __launch_bounds__(256) void oln_k(
    const short* __restrict__ ctx, const short* __restrict__ img,
    const float* __restrict__ bias, short* __restrict__ x,
    const float* __restrict__ g_, const float* __restrict__ b_) {
  __shared__ __align__(16) short sB[24576];
  int w = threadIdx.x >> 6, lane = threadIdx.x & 63;
  int l15 = lane & 15, g4 = lane >> 4;
  int r0 = blockIdx.x * 64 + w * 16;
  f32x4 acc[16];
#pragma unroll
  for (int i = 0; i < 16; ++i) acc[i] = f32x4{0.f, 0.f, 0.f, 0.f};
  gemm_core<8>(ctx, 256, img, sB, acc, r0, w, lane, l15, g4);
  ln_epi(acc, x, bias, g_, b_, r0, l15, g4);
}

// ---- FFN1: grid (1600, 2); gelu via exp; repacked coalesced h-store ----
__global__ __launch_bounds__(256) void ffn1_k(
    const short* __restrict__ x, const short* __restrict__ img,
    const float* __restrict__ bias, short* __restrict__ h) {
  __shared__ __align__(16) short sB[24576];
  int tid = threadIdx.x;
  int w = tid >> 6, lane = tid & 63;
  int l15 = lane & 15, g4 = lane >> 4;
  int y = blockIdx.y;
  int r0b = blockIdx.x * 64;
  f32x4 acc[16];
#pragma unroll
  for (int i = 0; i < 16; ++i) acc[i] = f32x4{0.f, 0.f, 0.f, 0.f};
  gemm_core<8>(x, 256, img + y * 65536, sB, acc, r0b + w * 16, w, lane, l15, g4);
  __syncthreads();  // stage buffer dead -> repack area
  const float* bs = bias + y * 256;
#pragma unroll
  for (int tc = 0; tc < 16; ++tc) {
    int col = tc * 16 + l15;
    float bv = bs[col];
#pragma unroll
    for (int r = 0; r < 4; ++r) {
      float v = acc[tc][r] + bv;
      // tanh-form GELU via exp: v * sigmoid(1.5957691*(v + 0.044715 v^3))
      float z = 1.5957691f * (v + 0.044715f * v * v * v);
      v = v / (1.f + __expf(-z));
      int lrow = w * 16 + g4 * 4 + r;
      sB[(lrow * 256 + col) ^ ((lrow & 7) << 3)] = (short)f2b(v);
    }
  }
  __syncthreads();
  short* dst = h + (size_t)r0b * 512 + y * 256;
#pragma unroll
  for (int i = 0; i < 8; ++i) {
    int j = i * 256 + tid;
    int row = j >> 5, c8 = j & 31;
    short8 v = *(const short8*)(sB + ((row * 256 + c8 * 8) ^ ((row & 7) << 3)));
    *(short8*)(dst + row * 512 + c8 * 8) = v;
  }
}

// ---- FFN2 + residual LN: x = LN(h@wout + outb + x) ----
__global__ __launch_bounds__(256) void ffn2_k(
    const short* __restrict__ h, const short* __restrict__ img,
    const float* __restrict__ bias, short* __restrict__ x,
    const float* __restrict__ g_, const float* __restrict__ b_) {
  __shared__ __align__(16) short sB[24576];
  int w = threadIdx.x >> 6, lane = threadIdx.x & 63;
  int l15 = lane & 15, g4 = lane >> 4;
  int r0 = blockIdx.x * 64 + w * 16;
  f32x4 acc[16];
#pragma unroll
  for (int i = 0; i < 16; ++i) acc[i] = f32x4{0.f, 0.f, 0.f, 0.f};
  gemm_core<16>(h, 512, img, sB, acc, r0, w, lane, l15, g4);
  ln_epi(acc, x, bias, g_, b_, r0, l15, g4);
}

// ---- pooler: 25 blocks; rows = seqs, A = first token of each seq ----
__global__ __launch_bounds__(256) void pool_k(
    const short* __restrict__ x, const short* __restrict__ img,
    const float* __restrict__ pb, float* __restrict__ out) {
  __shared__ __align__(16) short sB[24576];
  int w = threadIdx.x >> 6, lane = threadIdx.x & 63;
  int l15 = lane & 15, g4 = lane >> 4;
  int r0 = blockIdx.x * 64 + w * 16;  // seq index (25*64 = 1600 exact)
  f32x4 acc[16];
#pragma unroll
  for (int i = 0; i < 16; ++i) acc[i] = f32x4{0.f, 0.f, 0.f, 0.f};
  gemm_core<8>(x, 16384, img, sB, acc, r0, w, lane, l15, g4);
#pragma unroll
  for (int tc = 0; tc < 16; ++tc) {
    int col = tc * 16 + l15;
    float bv = pb[col];
#pragma unroll
    for (int r = 0; r < 4; ++r)
      out[(size_t)(r0 + g4 * 4 + r) * 256 + col] = tanhf(acc[tc][r] + bv);
  }
}

extern "C" void kernel_launch(void* const* d_in, const int* in_sizes, int n_in,
                              void* d_out, int out_size, void* d_ws, size_t ws_size,
                              hipStream_t stream) {
  const int* word = (const int*)d_in[0];
  const int* age = (const int*)d_in[1];
  const int* seg = (const int*)d_in[2];
  const int* posi = (const int*)d_in[3];
  const float* mask = (const float*)d_in[4];
  const float* word_emb = (const float*)d_in[6];
  const float* seg_emb = (const float*)d_in[7];
  const float* age_emb = (const float*)d_in[8];
  const float* posi_emb = (const float*)d_in[9];
  const float* emb_g = (const float*)d_in[10];
  const float* emb_b = (const float*)d_in[11];
  const float* qw = (const float*)d_in[12];
  const float* qb = (const float*)d_in[13];
  const float* kw = (const float*)d_in[14];
  const float* kb = (const float*)d_in[15];
  const float* vw = (const float*)d_in[16];
  const float* vb = (const float*)d_in[17];
  const float* ow = (const float*)d_in[18];
  const float* ob = (const float*)d_in[19];
  const float* attn_g = (const float*)d_in[20];
  const float* attn_b = (const float*)d_in[21];
  const float* iw = (const float*)d_in[22];
  const float* ib = (const float*)d_in[23];
  const float* outw = (const float*)d_in[24];
  const float* outb = (const float*)d_in[25];
  const float* out_g = (const float*)d_in[26];
  const float* out_b = (const float*)d_in[27];
  const float* pool_w = (const float*)d_in[28];
  const float* pool_b = (const float*)d_in[29];
  short* ws = (short*)d_ws;

  // layout (shorts): img 1,114,112 | x 26,214,400 | q | k | vt  (h = q..k span)
  short* xb_ = ws + 1114112;
  short* qbuf = xb_ + 26214400;
  short* kbuf = qbuf + 26214400;
  short* vtbuf = kbuf + 26214400;
  short* hbuf = qbuf;  // 102400x512, overlaps q+k (dead by FFN time)

  prep_w<<<4352, 256, 0, stream>>>(qw, kw, vw, ow, iw, outw, pool_w, ws);
  emb_k<<<25600, 256, 0, stream>>>(word, age, seg, posi, word_emb, seg_emb,
                                   age_emb, posi_emb, emb_g, emb_b, xb_);
  for (int ly = 0; ly < 2; ++ly) {
    qkv3_k<<<dim3(1600, 3), 256, 0, stream>>>(xb_, ws, qb, kb, vb, qbuf, kbuf,
                                              vtbuf, ly);
    attn_k<<<1600, 256, 0, stream>>>(qbuf, kbuf, vtbuf, qbuf, mask);
    oln_k<<<1600, 256, 0, stream>>>(qbuf, ws + 393216 + ly * 65536, ob + ly * 256,
                                    xb_, attn_g + ly * 256, attn_b + ly * 256);
    ffn1_k<<<dim3(1600, 2), 256, 0, stream>>>(xb_, ws + 524288 + ly * 131072,
                                              ib + ly * 512, hbuf);
    ffn2_k<<<1600, 256, 0, stream>>>(hbuf, ws + 786432 + ly * 131072,
                                     outb + ly * 256, xb_, out_g + ly * 256,
                                     out_b + ly * 256);
  }
  pool_k<<<25, 256, 0, stream>>>(xb_, ws + 1048576, pool_b, (float*)d_out);
}